// Round 7
// baseline (179.755 us; speedup 1.0000x reference)
//
#include <hip/hip_runtime.h>
#include <cstdint>
#include <cstddef>

#define DD 128
#define KK 32
constexpr float EPS = 1e-8f;

typedef __bf16 bf16x8 __attribute__((ext_vector_type(8)));
typedef float f32x4 __attribute__((ext_vector_type(4)));

__device__ __forceinline__ unsigned short f2bf(float x) {
    union { float f; uint32_t u; } v; v.f = x;
    uint32_t r = v.u + 0x7FFFu + ((v.u >> 16) & 1u);   // RNE
    return (unsigned short)(r >> 16);
}
__device__ __forceinline__ __bf16 f2bf16(float x) {
    unsigned short u = f2bf(x);
    __bf16 r; __builtin_memcpy(&r, &u, 2); return r;
}
// pack 8 floats -> 8 bf16 in a uint4 (one 16B store)
__device__ __forceinline__ uint4 pack8(float4 a, float4 b) {
    uint4 o;
    o.x = (uint32_t)f2bf(a.x) | ((uint32_t)f2bf(a.y) << 16);
    o.y = (uint32_t)f2bf(a.z) | ((uint32_t)f2bf(a.w) << 16);
    o.z = (uint32_t)f2bf(b.x) | ((uint32_t)f2bf(b.y) << 16);
    o.w = (uint32_t)f2bf(b.z) | ((uint32_t)f2bf(b.w) << 16);
    return o;
}

// DPP quad_perm fold over lane-xor 1,2 (VALU pipe, no LDS).
template <int CTRL>
__device__ __forceinline__ float dpp_fold(float x) {
    union { float f; int i; } u, r;
    u.f = x;
    r.i = __builtin_amdgcn_update_dpp(0, u.i, CTRL, 0xF, 0xF, false);
    return x + r.f;
}
__device__ __forceinline__ f32x4 fold4(f32x4 v) {
    #pragma unroll
    for (int c = 0; c < 4; ++c) {
        float x = v[c];
        x = dpp_fold<0xB1>(x);   // xor 1
        x = dpp_fold<0x4E>(x);   // xor 2
        v[c] = x;
    }
    return v;
}

// ---------------- prep kernel: cvt + wf + FUSED part2 (r4 proven) -----------
__global__ __launch_bounds__(256) void prep_kernel(
    const float* __restrict__ x1, const float* __restrict__ x2,
    const float* __restrict__ W1, const float* __restrict__ W2,
    const float* __restrict__ V,
    __bf16* __restrict__ X1f, __bf16* __restrict__ X2f,
    __bf16* __restrict__ W1f, __bf16* __restrict__ W2f,
    float* __restrict__ p2,            // [2][KK][N]
    int cvt_half, int wf_half)
{
    __shared__ float tile[16][132];   // 8.4 KB, +4 pad
    const int nTot = cvt_half * 16;
    int bb = blockIdx.x;
    if (bb < 2 * cvt_half) {
        const float* src; __bf16* dst; int half;
        if (bb >= cvt_half) { src = x2; dst = X2f; half = 1; bb -= cvt_half; }
        else                { src = x1; dst = X1f; half = 0; }
        const int rg = bb;
        {
            const int row = threadIdx.x >> 4;
            const int c8  = (threadIdx.x & 15) * 8;
            const float* p = src + (size_t)(rg * 16 + row) * DD + c8;
            float4 f0 = *reinterpret_cast<const float4*>(p);
            float4 f1 = *reinterpret_cast<const float4*>(p + 4);
            *reinterpret_cast<float4*>(&tile[row][c8])     = f0;
            *reinterpret_cast<float4*>(&tile[row][c8 + 4]) = f1;
        }
        __syncthreads();
        {
            const int mm = threadIdx.x & 15;
            const int c  = threadIdx.x >> 4;
            float4 a = *reinterpret_cast<float4*>(&tile[mm][c * 8]);
            float4 b = *reinterpret_cast<float4*>(&tile[mm][c * 8 + 4]);
            size_t off = (size_t)rg * 2048 + (size_t)c * 128 + (size_t)mm * 8;
            *reinterpret_cast<uint4*>(dst + off) = pack8(a, b);
        }
        // ---- fused part2 half-dot: waves 0,1 only (ct = wave) ----
        const int wave = threadIdx.x >> 6;
        if (wave < 2) {
            const int lane = threadIdx.x & 63;
            const int m    = lane & 15;
            const int quad = lane >> 4;
            const int ct   = wave;
            bf16x8 a[4], bf[4];
            #pragma unroll
            for (int ks = 0; ks < 4; ++ks) {
                float4 a0 = *reinterpret_cast<float4*>(&tile[m][ks * 32 + quad * 8]);
                float4 a1 = *reinterpret_cast<float4*>(&tile[m][ks * 32 + quad * 8 + 4]);
                bf16x8 t;
                t[0] = f2bf16(a0.x); t[1] = f2bf16(a0.y);
                t[2] = f2bf16(a0.z); t[3] = f2bf16(a0.w);
                t[4] = f2bf16(a1.x); t[5] = f2bf16(a1.y);
                t[6] = f2bf16(a1.z); t[7] = f2bf16(a1.w);
                a[ks] = t;
                const float* Vp = V + (size_t)(ct * 16 + m) * 256 + half * 128 + ks * 32 + quad * 8;
                float4 v0 = *reinterpret_cast<const float4*>(Vp);
                float4 v1 = *reinterpret_cast<const float4*>(Vp + 4);
                bf16x8 u;
                u[0] = f2bf16(v0.x); u[1] = f2bf16(v0.y);
                u[2] = f2bf16(v0.z); u[3] = f2bf16(v0.w);
                u[4] = f2bf16(v1.x); u[5] = f2bf16(v1.y);
                u[6] = f2bf16(v1.z); u[7] = f2bf16(v1.w);
                bf[ks] = u;
            }
            f32x4 acc = {0.f, 0.f, 0.f, 0.f};
            #pragma unroll
            for (int ks = 0; ks < 4; ++ks)
                acc = __builtin_amdgcn_mfma_f32_16x16x32_bf16(a[ks], bf[ks], acc, 0, 0, 0);
            float* p2h = p2 + (size_t)half * KK * nTot;
            *reinterpret_cast<f32x4*>(
                &p2h[(size_t)(ct * 16 + m) * nTot + rg * 16 + quad * 4]) = acc;
        }
    } else {
        bb -= 2 * cvt_half;
        const float* W; __bf16* Wf;
        if (bb >= wf_half) { W = W2; Wf = W2f; bb -= wf_half; }
        else               { W = W1; Wf = W1f; }
        int idx = bb * 256 + threadIdx.x;
        int mm = idx & 15;
        int c  = (idx >> 4) & 15;
        int eg = (idx >> 8) & 7;
        int k  = idx >> 11;
        const float* Wk = W + (size_t)k * DD * DD;
        int e = eg * 16 + mm;
        float4 a, b;
        a.x = Wk[(size_t)(c * 8 + 0) * DD + e];
        a.y = Wk[(size_t)(c * 8 + 1) * DD + e];
        a.z = Wk[(size_t)(c * 8 + 2) * DD + e];
        a.w = Wk[(size_t)(c * 8 + 3) * DD + e];
        b.x = Wk[(size_t)(c * 8 + 4) * DD + e];
        b.y = Wk[(size_t)(c * 8 + 5) * DD + e];
        b.z = Wk[(size_t)(c * 8 + 6) * DD + e];
        b.w = Wk[(size_t)(c * 8 + 7) * DD + e];
        size_t off = ((size_t)(k * 8 + eg)) * 2048 + (size_t)c * 128 + (size_t)mm * 8;
        *reinterpret_cast<uint4*>(Wf + off) = pack8(a, b);
    }
}

// ---------------- main fused kernel: occupancy-first restructure ------------
// Grid 4096 = 32 k x 128 row-groups (256 rows). Block = 4 waves; wave = one
// e-QUARTER (eh = wave, 32 cols of BOTH mats) -> Bc halves to 64 regs/wave,
// per-wave total ~145 regs -> 3 waves/SIMD (12 waves/CU, was 8). Tiles are
// 16 rows; 16-deep barrier-free g-loop (waves drift); all 4 waves load the
// SAME A fragments (L1 broadcast). sRed packs to [16][3][4][4][16] = 48 KB
// -> 3 blocks/CU within 160 KB LDS. Single barrier, then 256-thread epilogue
// (p2 read coalesced from transposed planes).
__global__ __launch_bounds__(256, 3) void ntn_main(
    const __bf16* __restrict__ X1f, const __bf16* __restrict__ X2f,
    const __bf16* __restrict__ W1f, const __bf16* __restrict__ W2f,
    const float* __restrict__ p2, const float* __restrict__ bias,
    float* __restrict__ out, int grp_per_xcd, int nTot)
{
    __shared__ __align__(16) float sRedAll[16][3][4][4][16];   // 48 KB

    const int b    = blockIdx.x;
    const int xcd  = b & 7;
    const int k    = (b >> 3) & 31;
    const int grpN = xcd * grp_per_xcd + (b >> 8);   // 256-row group
    const int tid  = threadIdx.x;
    const int eh   = tid >> 6;      // wave = e-quarter (32 cols)
    const int lane = tid & 63;
    const int m    = lane & 15;
    const int quad = lane >> 4;

    const __bf16* W1p = W1f + (size_t)k * 16384;
    const __bf16* W2p = W2f + (size_t)k * 16384;

    // ---- cache this wave's B quarter: 2 mats x 4 ks x 2 et = 64 regs ----
    bf16x8 Bc[2][4][2];
    #pragma unroll
    for (int ks = 0; ks < 4; ++ks)
        #pragma unroll
        for (int et = 0; et < 2; ++et) {
            const size_t boff = (size_t)(eh * 2 + et) * 2048 + ks * 512 + lane * 8;
            Bc[0][ks][et] = *reinterpret_cast<const bf16x8*>(W1p + boff);
            Bc[1][ks][et] = *reinterpret_cast<const bf16x8*>(W2p + boff);
        }

    const int rg0 = grpN * 16;
    const size_t lane8 = (size_t)lane * 8;

    // ---- preload tile 0's A fragments (identical across waves -> L1) ----
    bf16x8 a1[4], a2[4];
    {
        const size_t ab = (size_t)rg0 * 2048 + lane8;
        #pragma unroll
        for (int ks = 0; ks < 4; ++ks) {
            a1[ks] = *reinterpret_cast<const bf16x8*>(X1f + ab + ks * 512);
            a2[ks] = *reinterpret_cast<const bf16x8*>(X2f + ab + ks * 512);
        }
    }

    const f32x4 z = {0.f, 0.f, 0.f, 0.f};   // hoisted zero quad (C of ks=0)

    #pragma unroll
    for (int g = 0; g < 16; ++g) {
        f32x4 acc[2][2];    // [mat][et] — written by ks=0 MFMA, no init
        #pragma unroll
        for (int et = 0; et < 2; ++et) {
            acc[0][et] = __builtin_amdgcn_mfma_f32_16x16x32_bf16(a1[0], Bc[0][0][et], z, 0, 0, 0);
            acc[1][et] = __builtin_amdgcn_mfma_f32_16x16x32_bf16(a2[0], Bc[1][0][et], z, 0, 0, 0);
        }
        #pragma unroll
        for (int ks = 1; ks < 4; ++ks) {
            #pragma unroll
            for (int et = 0; et < 2; ++et) {
                acc[0][et] = __builtin_amdgcn_mfma_f32_16x16x32_bf16(a1[ks], Bc[0][ks][et], acc[0][et], 0, 0, 0);
                acc[1][et] = __builtin_amdgcn_mfma_f32_16x16x32_bf16(a2[ks], Bc[1][ks][et], acc[1][et], 0, 0, 0);
            }
        }

        // ---- prefetch tile g+1's A fragments ----
        if (g < 15) {
            const size_t ab = (size_t)(rg0 + g + 1) * 2048 + lane8;
            #pragma unroll
            for (int ks = 0; ks < 4; ++ks) {
                a1[ks] = *reinterpret_cast<const bf16x8*>(X1f + ab + ks * 512);
                a2[ks] = *reinterpret_cast<const bf16x8*>(X2f + ab + ks * 512);
            }
        }

        // ---- in-register cross-mat products + DPP folds -> LDS slice ----
        f32x4 pd = {0.f, 0.f, 0.f, 0.f};
        f32x4 q1 = {0.f, 0.f, 0.f, 0.f};
        f32x4 q2 = {0.f, 0.f, 0.f, 0.f};
        #pragma unroll
        for (int et = 0; et < 2; ++et) {
            f32x4 c1 = acc[0][et];
            f32x4 c2 = acc[1][et];
            pd += c1 * c2;
            q1 += c1 * c1;
            q2 += c2 * c2;
        }
        pd = fold4(pd);
        q1 = fold4(q1);
        q2 = fold4(q2);

        if ((m & 3) == 0) {
            const int grp = m >> 2;          // 4 groups of (4 m-cols x 2 et)
            *reinterpret_cast<f32x4*>(&sRedAll[g][0][eh][grp][quad * 4]) = pd;
            *reinterpret_cast<f32x4*>(&sRedAll[g][1][eh][grp][quad * 4]) = q1;
            *reinterpret_cast<f32x4*>(&sRedAll[g][2][eh][grp][quad * 4]) = q2;
        }
        // NO barrier here — waves drift through tiles independently.
    }

    __syncthreads();   // the ONLY barrier: all 16 tiles' partials visible

    // ---- output: thread t -> tile = t>>4, row = t&15 (n = grpN*256 + t) ----
    {
        const int tile = tid >> 4;
        const int row  = tid & 15;
        const size_t nOut = (size_t)grpN * 256 + tid;
        const size_t p2idx = (size_t)k * nTot + nOut;
        const float p2v = p2[p2idx] + p2[p2idx + (size_t)KK * nTot];
        const float bk  = bias[k];
        float dot = 0.f, s1 = 0.f, s2 = 0.f;
        #pragma unroll
        for (int e2 = 0; e2 < 4; ++e2)
            #pragma unroll
            for (int gg = 0; gg < 4; ++gg) {
                dot += sRedAll[tile][0][e2][gg][row];
                s1  += sRedAll[tile][1][e2][gg][row];
                s2  += sRedAll[tile][2][e2][gg][row];
            }
        float n1 = fmaxf(sqrtf(s1), EPS);
        float n2 = fmaxf(sqrtf(s2), EPS);
        float tot = dot / (n1 * n2) + p2v + bk;
        out[nOut * KK + k] = fmaxf(tot, 0.f);
    }
}

extern "C" void kernel_launch(void* const* d_in, const int* in_sizes, int n_in,
                              void* d_out, int out_size, void* d_ws, size_t ws_size,
                              hipStream_t stream) {
    const float* x1 = (const float*)d_in[0];
    const float* x2 = (const float*)d_in[1];
    const float* W1 = (const float*)d_in[2];
    const float* W2 = (const float*)d_in[3];
    const float* V  = (const float*)d_in[4];
    const float* b  = (const float*)d_in[5];
    float* out = (float*)d_out;

    const int N = in_sizes[0] / DD;   // 32768

    __bf16* X1f = (__bf16*)d_ws;
    __bf16* X2f = X1f + (size_t)N * DD;
    __bf16* W1f = X2f + (size_t)N * DD;
    __bf16* W2f = W1f + (size_t)KK * DD * DD;
    float*  p2  = (float*)(W2f + (size_t)KK * DD * DD);   // [2][KK][N]

    const int cvt_half = N / 16;                  // 2048 blocks per tensor
    const int wf_half  = KK * DD * DD / 8 / 256;  // 256
    prep_kernel<<<2 * cvt_half + 2 * wf_half, 256, 0, stream>>>(
        x1, x2, W1, W2, V, X1f, X2f, W1f, W2f, p2, cvt_half, wf_half);

    const int groups = N / 256;                   // 128
    ntn_main<<<groups * KK, 256, 0, stream>>>(X1f, X2f, W1f, W2f, p2, b, out,
                                              groups / 8, N);
}

// Round 8
// 159.798 us; speedup vs baseline: 1.1249x; 1.1249x over previous
//
#include <hip/hip_runtime.h>
#include <cstdint>
#include <cstddef>

#define DD 128
#define KK 32
constexpr float EPS = 1e-8f;

typedef __bf16 bf16x8 __attribute__((ext_vector_type(8)));
typedef float f32x4 __attribute__((ext_vector_type(4)));

__device__ __forceinline__ unsigned short f2bf(float x) {
    union { float f; uint32_t u; } v; v.f = x;
    uint32_t r = v.u + 0x7FFFu + ((v.u >> 16) & 1u);   // RNE
    return (unsigned short)(r >> 16);
}
__device__ __forceinline__ __bf16 f2bf16(float x) {
    unsigned short u = f2bf(x);
    __bf16 r; __builtin_memcpy(&r, &u, 2); return r;
}
// pack 8 floats -> 8 bf16 in a uint4 (one 16B store)
__device__ __forceinline__ uint4 pack8(float4 a, float4 b) {
    uint4 o;
    o.x = (uint32_t)f2bf(a.x) | ((uint32_t)f2bf(a.y) << 16);
    o.y = (uint32_t)f2bf(a.z) | ((uint32_t)f2bf(a.w) << 16);
    o.z = (uint32_t)f2bf(b.x) | ((uint32_t)f2bf(b.y) << 16);
    o.w = (uint32_t)f2bf(b.z) | ((uint32_t)f2bf(b.w) << 16);
    return o;
}

// DPP quad_perm fold over lane-xor 1 (VALU pipe, no LDS).
template <int CTRL>
__device__ __forceinline__ float dpp_fold(float x) {
    union { float f; int i; } u, r;
    u.f = x;
    r.i = __builtin_amdgcn_update_dpp(0, u.i, CTRL, 0xF, 0xF, false);
    return x + r.f;
}
__device__ __forceinline__ f32x4 fold1(f32x4 v) {
    #pragma unroll
    for (int c = 0; c < 4; ++c) v[c] = dpp_fold<0xB1>(v[c]);   // xor 1
    return v;
}

// ---------------- prep kernel: cvt + wf + FUSED part2 (r4 proven) -----------
__global__ __launch_bounds__(256) void prep_kernel(
    const float* __restrict__ x1, const float* __restrict__ x2,
    const float* __restrict__ W1, const float* __restrict__ W2,
    const float* __restrict__ V,
    __bf16* __restrict__ X1f, __bf16* __restrict__ X2f,
    __bf16* __restrict__ W1f, __bf16* __restrict__ W2f,
    float* __restrict__ p2,            // [2][KK][N]
    int cvt_half, int wf_half)
{
    __shared__ float tile[16][132];   // 8.4 KB, +4 pad
    const int nTot = cvt_half * 16;
    int bb = blockIdx.x;
    if (bb < 2 * cvt_half) {
        const float* src; __bf16* dst; int half;
        if (bb >= cvt_half) { src = x2; dst = X2f; half = 1; bb -= cvt_half; }
        else                { src = x1; dst = X1f; half = 0; }
        const int rg = bb;
        {
            const int row = threadIdx.x >> 4;
            const int c8  = (threadIdx.x & 15) * 8;
            const float* p = src + (size_t)(rg * 16 + row) * DD + c8;
            float4 f0 = *reinterpret_cast<const float4*>(p);
            float4 f1 = *reinterpret_cast<const float4*>(p + 4);
            *reinterpret_cast<float4*>(&tile[row][c8])     = f0;
            *reinterpret_cast<float4*>(&tile[row][c8 + 4]) = f1;
        }
        __syncthreads();
        {
            const int mm = threadIdx.x & 15;
            const int c  = threadIdx.x >> 4;
            float4 a = *reinterpret_cast<float4*>(&tile[mm][c * 8]);
            float4 b = *reinterpret_cast<float4*>(&tile[mm][c * 8 + 4]);
            size_t off = (size_t)rg * 2048 + (size_t)c * 128 + (size_t)mm * 8;
            *reinterpret_cast<uint4*>(dst + off) = pack8(a, b);
        }
        // ---- fused part2 half-dot: waves 0,1 only (ct = wave) ----
        const int wave = threadIdx.x >> 6;
        if (wave < 2) {
            const int lane = threadIdx.x & 63;
            const int m    = lane & 15;
            const int quad = lane >> 4;
            const int ct   = wave;
            bf16x8 a[4], bf[4];
            #pragma unroll
            for (int ks = 0; ks < 4; ++ks) {
                float4 a0 = *reinterpret_cast<float4*>(&tile[m][ks * 32 + quad * 8]);
                float4 a1 = *reinterpret_cast<float4*>(&tile[m][ks * 32 + quad * 8 + 4]);
                bf16x8 t;
                t[0] = f2bf16(a0.x); t[1] = f2bf16(a0.y);
                t[2] = f2bf16(a0.z); t[3] = f2bf16(a0.w);
                t[4] = f2bf16(a1.x); t[5] = f2bf16(a1.y);
                t[6] = f2bf16(a1.z); t[7] = f2bf16(a1.w);
                a[ks] = t;
                const float* Vp = V + (size_t)(ct * 16 + m) * 256 + half * 128 + ks * 32 + quad * 8;
                float4 v0 = *reinterpret_cast<const float4*>(Vp);
                float4 v1 = *reinterpret_cast<const float4*>(Vp + 4);
                bf16x8 u;
                u[0] = f2bf16(v0.x); u[1] = f2bf16(v0.y);
                u[2] = f2bf16(v0.z); u[3] = f2bf16(v0.w);
                u[4] = f2bf16(v1.x); u[5] = f2bf16(v1.y);
                u[6] = f2bf16(v1.z); u[7] = f2bf16(v1.w);
                bf[ks] = u;
            }
            f32x4 acc = {0.f, 0.f, 0.f, 0.f};
            #pragma unroll
            for (int ks = 0; ks < 4; ++ks)
                acc = __builtin_amdgcn_mfma_f32_16x16x32_bf16(a[ks], bf[ks], acc, 0, 0, 0);
            float* p2h = p2 + (size_t)half * KK * nTot;
            *reinterpret_cast<f32x4*>(
                &p2h[(size_t)(ct * 16 + m) * nTot + rg * 16 + quad * 4]) = acc;
        }
    } else {
        bb -= 2 * cvt_half;
        const float* W; __bf16* Wf;
        if (bb >= wf_half) { W = W2; Wf = W2f; bb -= wf_half; }
        else               { W = W1; Wf = W1f; }
        int idx = bb * 256 + threadIdx.x;
        int mm = idx & 15;
        int c  = (idx >> 4) & 15;
        int eg = (idx >> 8) & 7;
        int k  = idx >> 11;
        const float* Wk = W + (size_t)k * DD * DD;
        int e = eg * 16 + mm;
        float4 a, b;
        a.x = Wk[(size_t)(c * 8 + 0) * DD + e];
        a.y = Wk[(size_t)(c * 8 + 1) * DD + e];
        a.z = Wk[(size_t)(c * 8 + 2) * DD + e];
        a.w = Wk[(size_t)(c * 8 + 3) * DD + e];
        b.x = Wk[(size_t)(c * 8 + 4) * DD + e];
        b.y = Wk[(size_t)(c * 8 + 5) * DD + e];
        b.z = Wk[(size_t)(c * 8 + 6) * DD + e];
        b.w = Wk[(size_t)(c * 8 + 7) * DD + e];
        size_t off = ((size_t)(k * 8 + eg)) * 2048 + (size_t)c * 128 + (size_t)mm * 8;
        *reinterpret_cast<uint4*>(Wf + off) = pack8(a, b);
    }
}

// ---------------- main fused kernel: R6 + depth-2 A prefetch ----------------
// R6 structure (grid 4096 = 32 k x 128 groups, 256 rows/block, ONE barrier,
// fold1 VALU diet, no acc zero-init), with the A prefetch deepened to 2
// tiles via TWO NAMED register buffers (static indexing; 2-tile-unrolled
// loop). In R6 the tile-top s_waitcnt exposed ~100-250 cyc of L2 latency
// every tile (prefetch was issued only ~150 VALU-cycles before use, with
// just 2 waves/SIMD to cover). Now each buffer is refilled a FULL tile
// (~800 cyc) before consumption -> exposed latency ~0. +32 VGPR, still
// under the 2-wave/SIMD cap.
__global__ __launch_bounds__(256, 2) void ntn_main(
    const __bf16* __restrict__ X1f, const __bf16* __restrict__ X2f,
    const __bf16* __restrict__ W1f, const __bf16* __restrict__ W2f,
    const float* __restrict__ p2, const float* __restrict__ bias,
    float* __restrict__ out, int grp_per_xcd, int nTot)
{
    __shared__ __align__(16) float sRedAll[8][3][2][8][40];   // 61.4 KB

    const int b    = blockIdx.x;
    const int xcd  = b & 7;
    const int k    = (b >> 3) & 31;
    const int grpN = xcd * grp_per_xcd + (b >> 8);   // 256-row group
    const int tid  = threadIdx.x;
    const int wave = tid >> 6;
    const int lane = tid & 63;
    const int m    = lane & 15;
    const int quad = lane >> 4;
    const int rh   = wave & 1;      // row half of the 32-row tile
    const int eh   = wave >> 1;     // column half (64 cols)

    const __bf16* W1p = W1f + (size_t)k * 16384;
    const __bf16* W2p = W2f + (size_t)k * 16384;

    // ---- cache BOTH B halves in registers: 2 mats x 4 ks x 4 et ----
    bf16x8 Bc[2][4][4];
    #pragma unroll
    for (int ks = 0; ks < 4; ++ks)
        #pragma unroll
        for (int et = 0; et < 4; ++et) {
            const size_t boff = (size_t)(eh * 4 + et) * 2048 + ks * 512 + lane * 8;
            Bc[0][ks][et] = *reinterpret_cast<const bf16x8*>(W1p + boff);
            Bc[1][ks][et] = *reinterpret_cast<const bf16x8*>(W2p + boff);
        }

    const int rg0 = grpN * 16;
    const size_t lane8 = (size_t)lane * 8;

    // ---- depth-2 pipeline: named buffers A (even tiles) / B (odd tiles) ----
    bf16x8 a1A[4], a2A[4], a1B[4], a2B[4];
    {
        const size_t abA = (size_t)(rg0 + 0 * 2 + rh) * 2048 + lane8;
        const size_t abB = (size_t)(rg0 + 1 * 2 + rh) * 2048 + lane8;
        #pragma unroll
        for (int ks = 0; ks < 4; ++ks) {
            a1A[ks] = *reinterpret_cast<const bf16x8*>(X1f + abA + ks * 512);
            a2A[ks] = *reinterpret_cast<const bf16x8*>(X2f + abA + ks * 512);
            a1B[ks] = *reinterpret_cast<const bf16x8*>(X1f + abB + ks * 512);
            a2B[ks] = *reinterpret_cast<const bf16x8*>(X2f + abB + ks * 512);
        }
    }

    const f32x4 z = {0.f, 0.f, 0.f, 0.f};   // hoisted zero quad (C of ks=0)

    // one tile body: compute from (a1,a2), then refill them with tile 'pf'
    // (guarded), then fold+store partials for slot g.
#define TILE_BODY(a1, a2, g, pf)                                               \
    {                                                                          \
        f32x4 acc[2][4];                                                       \
        _Pragma("unroll")                                                      \
        for (int et = 0; et < 4; ++et) {                                       \
            acc[0][et] = __builtin_amdgcn_mfma_f32_16x16x32_bf16(a1[0], Bc[0][0][et], z, 0, 0, 0); \
            acc[1][et] = __builtin_amdgcn_mfma_f32_16x16x32_bf16(a2[0], Bc[1][0][et], z, 0, 0, 0); \
        }                                                                      \
        _Pragma("unroll")                                                      \
        for (int ks = 1; ks < 4; ++ks) {                                       \
            _Pragma("unroll")                                                  \
            for (int et = 0; et < 4; ++et) {                                   \
                acc[0][et] = __builtin_amdgcn_mfma_f32_16x16x32_bf16(a1[ks], Bc[0][ks][et], acc[0][et], 0, 0, 0); \
                acc[1][et] = __builtin_amdgcn_mfma_f32_16x16x32_bf16(a2[ks], Bc[1][ks][et], acc[1][et], 0, 0, 0); \
            }                                                                  \
        }                                                                      \
        if ((pf) < 8) {                                                        \
            const size_t ab = (size_t)(rg0 + (pf) * 2 + rh) * 2048 + lane8;    \
            _Pragma("unroll")                                                  \
            for (int ks = 0; ks < 4; ++ks) {                                   \
                a1[ks] = *reinterpret_cast<const bf16x8*>(X1f + ab + ks * 512);\
                a2[ks] = *reinterpret_cast<const bf16x8*>(X2f + ab + ks * 512);\
            }                                                                  \
        }                                                                      \
        f32x4 pd = {0.f, 0.f, 0.f, 0.f};                                       \
        f32x4 q1 = {0.f, 0.f, 0.f, 0.f};                                       \
        f32x4 q2 = {0.f, 0.f, 0.f, 0.f};                                       \
        _Pragma("unroll")                                                      \
        for (int et = 0; et < 4; ++et) {                                       \
            f32x4 c1 = acc[0][et];                                             \
            f32x4 c2 = acc[1][et];                                             \
            pd += c1 * c2;                                                     \
            q1 += c1 * c1;                                                     \
            q2 += c2 * c2;                                                     \
        }                                                                      \
        pd = fold1(pd);                                                        \
        q1 = fold1(q1);                                                        \
        q2 = fold1(q2);                                                        \
        if ((m & 1) == 0) {                                                    \
            const int grp = m >> 1;                                            \
            const int rb  = rh * 16 + quad * 4;                                \
            *reinterpret_cast<f32x4*>(&sRedAll[(g)][0][eh][grp][rb]) = pd;     \
            *reinterpret_cast<f32x4*>(&sRedAll[(g)][1][eh][grp][rb]) = q1;     \
            *reinterpret_cast<f32x4*>(&sRedAll[(g)][2][eh][grp][rb]) = q2;     \
        }                                                                      \
    }

    #pragma unroll
    for (int gp = 0; gp < 4; ++gp) {
        TILE_BODY(a1A, a2A, 2 * gp,     2 * gp + 2)   // even tile
        TILE_BODY(a1B, a2B, 2 * gp + 1, 2 * gp + 3)   // odd tile
    }
#undef TILE_BODY

    __syncthreads();   // the ONLY barrier: all 8 tiles' partials visible

    // ---- output: thread t -> tile = t>>5, row = t&31 (n = grpN*256 + t) ----
    {
        const int tile = tid >> 5;
        const int row  = tid & 31;
        const size_t nOut = (size_t)grpN * 256 + tid;
        const size_t p2idx = (size_t)k * nTot + nOut;
        const float p2v = p2[p2idx] + p2[p2idx + (size_t)KK * nTot];
        const float bk  = bias[k];
        float dot = 0.f, s1 = 0.f, s2 = 0.f;
        #pragma unroll
        for (int e2 = 0; e2 < 2; ++e2)
            #pragma unroll
            for (int gg = 0; gg < 8; ++gg) {
                dot += sRedAll[tile][0][e2][gg][row];
                s1  += sRedAll[tile][1][e2][gg][row];
                s2  += sRedAll[tile][2][e2][gg][row];
            }
        float n1 = fmaxf(sqrtf(s1), EPS);
        float n2 = fmaxf(sqrtf(s2), EPS);
        float tot = dot / (n1 * n2) + p2v + bk;
        out[nOut * KK + k] = fmaxf(tot, 0.f);
    }
}

extern "C" void kernel_launch(void* const* d_in, const int* in_sizes, int n_in,
                              void* d_out, int out_size, void* d_ws, size_t ws_size,
                              hipStream_t stream) {
    const float* x1 = (const float*)d_in[0];
    const float* x2 = (const float*)d_in[1];
    const float* W1 = (const float*)d_in[2];
    const float* W2 = (const float*)d_in[3];
    const float* V  = (const float*)d_in[4];
    const float* b  = (const float*)d_in[5];
    float* out = (float*)d_out;

    const int N = in_sizes[0] / DD;   // 32768

    __bf16* X1f = (__bf16*)d_ws;
    __bf16* X2f = X1f + (size_t)N * DD;
    __bf16* W1f = X2f + (size_t)N * DD;
    __bf16* W2f = W1f + (size_t)KK * DD * DD;
    float*  p2  = (float*)(W2f + (size_t)KK * DD * DD);   // [2][KK][N]

    const int cvt_half = N / 16;                  // 2048 blocks per tensor
    const int wf_half  = KK * DD * DD / 8 / 256;  // 256
    prep_kernel<<<2 * cvt_half + 2 * wf_half, 256, 0, stream>>>(
        x1, x2, W1, W2, V, X1f, X2f, W1f, W2f, p2, cvt_half, wf_half);

    const int groups = N / 256;                   // 128
    ntn_main<<<groups * KK, 256, 0, stream>>>(X1f, X2f, W1f, W2f, p2, b, out,
                                              groups / 8, N);
}

// Round 9
// 159.209 us; speedup vs baseline: 1.1291x; 1.0037x over previous
//
#include <hip/hip_runtime.h>
#include <cstdint>
#include <cstddef>

#define DD 128
#define KK 32
constexpr float EPS = 1e-8f;

typedef __bf16 bf16x8 __attribute__((ext_vector_type(8)));
typedef float f32x4 __attribute__((ext_vector_type(4)));

__device__ __forceinline__ unsigned short f2bf(float x) {
    union { float f; uint32_t u; } v; v.f = x;
    uint32_t r = v.u + 0x7FFFu + ((v.u >> 16) & 1u);   // RNE
    return (unsigned short)(r >> 16);
}
__device__ __forceinline__ __bf16 f2bf16(float x) {
    unsigned short u = f2bf(x);
    __bf16 r; __builtin_memcpy(&r, &u, 2); return r;
}
// pack 8 floats -> 8 bf16 in a uint4 (one 16B store)
__device__ __forceinline__ uint4 pack8(float4 a, float4 b) {
    uint4 o;
    o.x = (uint32_t)f2bf(a.x) | ((uint32_t)f2bf(a.y) << 16);
    o.y = (uint32_t)f2bf(a.z) | ((uint32_t)f2bf(a.w) << 16);
    o.z = (uint32_t)f2bf(b.x) | ((uint32_t)f2bf(b.y) << 16);
    o.w = (uint32_t)f2bf(b.z) | ((uint32_t)f2bf(b.w) << 16);
    return o;
}

// DPP quad_perm fold over lane-xor 1 (VALU pipe, no LDS).
template <int CTRL>
__device__ __forceinline__ float dpp_fold(float x) {
    union { float f; int i; } u, r;
    u.f = x;
    r.i = __builtin_amdgcn_update_dpp(0, u.i, CTRL, 0xF, 0xF, false);
    return x + r.f;
}
__device__ __forceinline__ f32x4 fold1(f32x4 v) {
    #pragma unroll
    for (int c = 0; c < 4; ++c) v[c] = dpp_fold<0xB1>(v[c]);   // xor 1
    return v;
}

// ---------------- prep kernel: cvt + wf + FUSED part2 (r4 proven) -----------
__global__ __launch_bounds__(256) void prep_kernel(
    const float* __restrict__ x1, const float* __restrict__ x2,
    const float* __restrict__ W1, const float* __restrict__ W2,
    const float* __restrict__ V,
    __bf16* __restrict__ X1f, __bf16* __restrict__ X2f,
    __bf16* __restrict__ W1f, __bf16* __restrict__ W2f,
    float* __restrict__ p2,            // [2][KK][N]
    int cvt_half, int wf_half)
{
    __shared__ float tile[16][132];   // 8.4 KB, +4 pad
    const int nTot = cvt_half * 16;
    int bb = blockIdx.x;
    if (bb < 2 * cvt_half) {
        const float* src; __bf16* dst; int half;
        if (bb >= cvt_half) { src = x2; dst = X2f; half = 1; bb -= cvt_half; }
        else                { src = x1; dst = X1f; half = 0; }
        const int rg = bb;
        {
            const int row = threadIdx.x >> 4;
            const int c8  = (threadIdx.x & 15) * 8;
            const float* p = src + (size_t)(rg * 16 + row) * DD + c8;
            float4 f0 = *reinterpret_cast<const float4*>(p);
            float4 f1 = *reinterpret_cast<const float4*>(p + 4);
            *reinterpret_cast<float4*>(&tile[row][c8])     = f0;
            *reinterpret_cast<float4*>(&tile[row][c8 + 4]) = f1;
        }
        __syncthreads();
        {
            const int mm = threadIdx.x & 15;
            const int c  = threadIdx.x >> 4;
            float4 a = *reinterpret_cast<float4*>(&tile[mm][c * 8]);
            float4 b = *reinterpret_cast<float4*>(&tile[mm][c * 8 + 4]);
            size_t off = (size_t)rg * 2048 + (size_t)c * 128 + (size_t)mm * 8;
            *reinterpret_cast<uint4*>(dst + off) = pack8(a, b);
        }
        // ---- fused part2 half-dot: waves 0,1 only (ct = wave) ----
        const int wave = threadIdx.x >> 6;
        if (wave < 2) {
            const int lane = threadIdx.x & 63;
            const int m    = lane & 15;
            const int quad = lane >> 4;
            const int ct   = wave;
            bf16x8 a[4], bf[4];
            #pragma unroll
            for (int ks = 0; ks < 4; ++ks) {
                float4 a0 = *reinterpret_cast<float4*>(&tile[m][ks * 32 + quad * 8]);
                float4 a1 = *reinterpret_cast<float4*>(&tile[m][ks * 32 + quad * 8 + 4]);
                bf16x8 t;
                t[0] = f2bf16(a0.x); t[1] = f2bf16(a0.y);
                t[2] = f2bf16(a0.z); t[3] = f2bf16(a0.w);
                t[4] = f2bf16(a1.x); t[5] = f2bf16(a1.y);
                t[6] = f2bf16(a1.z); t[7] = f2bf16(a1.w);
                a[ks] = t;
                const float* Vp = V + (size_t)(ct * 16 + m) * 256 + half * 128 + ks * 32 + quad * 8;
                float4 v0 = *reinterpret_cast<const float4*>(Vp);
                float4 v1 = *reinterpret_cast<const float4*>(Vp + 4);
                bf16x8 u;
                u[0] = f2bf16(v0.x); u[1] = f2bf16(v0.y);
                u[2] = f2bf16(v0.z); u[3] = f2bf16(v0.w);
                u[4] = f2bf16(v1.x); u[5] = f2bf16(v1.y);
                u[6] = f2bf16(v1.z); u[7] = f2bf16(v1.w);
                bf[ks] = u;
            }
            f32x4 acc = {0.f, 0.f, 0.f, 0.f};
            #pragma unroll
            for (int ks = 0; ks < 4; ++ks)
                acc = __builtin_amdgcn_mfma_f32_16x16x32_bf16(a[ks], bf[ks], acc, 0, 0, 0);
            float* p2h = p2 + (size_t)half * KK * nTot;
            *reinterpret_cast<f32x4*>(
                &p2h[(size_t)(ct * 16 + m) * nTot + rg * 16 + quad * 4]) = acc;
        }
    } else {
        bb -= 2 * cvt_half;
        const float* W; __bf16* Wf;
        if (bb >= wf_half) { W = W2; Wf = W2f; bb -= wf_half; }
        else               { W = W1; Wf = W1f; }
        int idx = bb * 256 + threadIdx.x;
        int mm = idx & 15;
        int c  = (idx >> 4) & 15;
        int eg = (idx >> 8) & 7;
        int k  = idx >> 11;
        const float* Wk = W + (size_t)k * DD * DD;
        int e = eg * 16 + mm;
        float4 a, b;
        a.x = Wk[(size_t)(c * 8 + 0) * DD + e];
        a.y = Wk[(size_t)(c * 8 + 1) * DD + e];
        a.z = Wk[(size_t)(c * 8 + 2) * DD + e];
        a.w = Wk[(size_t)(c * 8 + 3) * DD + e];
        b.x = Wk[(size_t)(c * 8 + 4) * DD + e];
        b.y = Wk[(size_t)(c * 8 + 5) * DD + e];
        b.z = Wk[(size_t)(c * 8 + 6) * DD + e];
        b.w = Wk[(size_t)(c * 8 + 7) * DD + e];
        size_t off = ((size_t)(k * 8 + eg)) * 2048 + (size_t)c * 128 + (size_t)mm * 8;
        *reinterpret_cast<uint4*>(Wf + off) = pack8(a, b);
    }
}

// ---------------- main fused kernel: R8 + hidden p2 latency + nt hints ------
// R8 structure (grid 4096 = 32 k x 128 groups, 256 rows/block, ONE barrier,
// fold1 VALU diet, depth-2 named A buffers). Changes:
//  1. p2 loads ISSUED IN PROLOGUE (nontemporal) -> their ~300-900 cyc HBM/L3
//     latency hides under the whole g-loop instead of sitting exposed in the
//     epilogue.
//  2. nontemporal on p2 loads + out store: both are touched exactly once;
//     keeps the 12 MB of streaming traffic from evicting the hot W/X working
//     set (~2.3 MB) in the 4 MB/XCD L2.
__global__ __launch_bounds__(256, 2) void ntn_main(
    const __bf16* __restrict__ X1f, const __bf16* __restrict__ X2f,
    const __bf16* __restrict__ W1f, const __bf16* __restrict__ W2f,
    const float* __restrict__ p2, const float* __restrict__ bias,
    float* __restrict__ out, int grp_per_xcd, int nTot)
{
    __shared__ __align__(16) float sRedAll[8][3][2][8][40];   // 61.4 KB

    const int b    = blockIdx.x;
    const int xcd  = b & 7;
    const int k    = (b >> 3) & 31;
    const int grpN = xcd * grp_per_xcd + (b >> 8);   // 256-row group
    const int tid  = threadIdx.x;
    const int wave = tid >> 6;
    const int lane = tid & 63;
    const int m    = lane & 15;
    const int quad = lane >> 4;
    const int rh   = wave & 1;      // row half of the 32-row tile
    const int eh   = wave >> 1;     // column half (64 cols)

    // ---- issue p2/bias loads NOW; consumed after the barrier ----
    const size_t nOut = (size_t)grpN * 256 + tid;
    const size_t p2idx = (size_t)k * nTot + nOut;
    const float p2a = __builtin_nontemporal_load(p2 + p2idx);
    const float p2b = __builtin_nontemporal_load(p2 + p2idx + (size_t)KK * nTot);
    const float bk  = bias[k];

    const __bf16* W1p = W1f + (size_t)k * 16384;
    const __bf16* W2p = W2f + (size_t)k * 16384;

    // ---- cache BOTH B halves in registers: 2 mats x 4 ks x 4 et ----
    bf16x8 Bc[2][4][4];
    #pragma unroll
    for (int ks = 0; ks < 4; ++ks)
        #pragma unroll
        for (int et = 0; et < 4; ++et) {
            const size_t boff = (size_t)(eh * 4 + et) * 2048 + ks * 512 + lane * 8;
            Bc[0][ks][et] = *reinterpret_cast<const bf16x8*>(W1p + boff);
            Bc[1][ks][et] = *reinterpret_cast<const bf16x8*>(W2p + boff);
        }

    const int rg0 = grpN * 16;
    const size_t lane8 = (size_t)lane * 8;

    // ---- depth-2 pipeline: named buffers A (even tiles) / B (odd tiles) ----
    bf16x8 a1A[4], a2A[4], a1B[4], a2B[4];
    {
        const size_t abA = (size_t)(rg0 + 0 * 2 + rh) * 2048 + lane8;
        const size_t abB = (size_t)(rg0 + 1 * 2 + rh) * 2048 + lane8;
        #pragma unroll
        for (int ks = 0; ks < 4; ++ks) {
            a1A[ks] = *reinterpret_cast<const bf16x8*>(X1f + abA + ks * 512);
            a2A[ks] = *reinterpret_cast<const bf16x8*>(X2f + abA + ks * 512);
            a1B[ks] = *reinterpret_cast<const bf16x8*>(X1f + abB + ks * 512);
            a2B[ks] = *reinterpret_cast<const bf16x8*>(X2f + abB + ks * 512);
        }
    }

    const f32x4 z = {0.f, 0.f, 0.f, 0.f};   // hoisted zero quad (C of ks=0)

    // one tile body: compute from (a1,a2), then refill them with tile 'pf'
    // (guarded), then fold+store partials for slot g.
#define TILE_BODY(a1, a2, g, pf)                                               \
    {                                                                          \
        f32x4 acc[2][4];                                                       \
        _Pragma("unroll")                                                      \
        for (int et = 0; et < 4; ++et) {                                       \
            acc[0][et] = __builtin_amdgcn_mfma_f32_16x16x32_bf16(a1[0], Bc[0][0][et], z, 0, 0, 0); \
            acc[1][et] = __builtin_amdgcn_mfma_f32_16x16x32_bf16(a2[0], Bc[1][0][et], z, 0, 0, 0); \
        }                                                                      \
        _Pragma("unroll")                                                      \
        for (int ks = 1; ks < 4; ++ks) {                                       \
            _Pragma("unroll")                                                  \
            for (int et = 0; et < 4; ++et) {                                   \
                acc[0][et] = __builtin_amdgcn_mfma_f32_16x16x32_bf16(a1[ks], Bc[0][ks][et], acc[0][et], 0, 0, 0); \
                acc[1][et] = __builtin_amdgcn_mfma_f32_16x16x32_bf16(a2[ks], Bc[1][ks][et], acc[1][et], 0, 0, 0); \
            }                                                                  \
        }                                                                      \
        if ((pf) < 8) {                                                        \
            const size_t ab = (size_t)(rg0 + (pf) * 2 + rh) * 2048 + lane8;    \
            _Pragma("unroll")                                                  \
            for (int ks = 0; ks < 4; ++ks) {                                   \
                a1[ks] = *reinterpret_cast<const bf16x8*>(X1f + ab + ks * 512);\
                a2[ks] = *reinterpret_cast<const bf16x8*>(X2f + ab + ks * 512);\
            }                                                                  \
        }                                                                      \
        f32x4 pd = {0.f, 0.f, 0.f, 0.f};                                       \
        f32x4 q1 = {0.f, 0.f, 0.f, 0.f};                                       \
        f32x4 q2 = {0.f, 0.f, 0.f, 0.f};                                       \
        _Pragma("unroll")                                                      \
        for (int et = 0; et < 4; ++et) {                                       \
            f32x4 c1 = acc[0][et];                                             \
            f32x4 c2 = acc[1][et];                                             \
            pd += c1 * c2;                                                     \
            q1 += c1 * c1;                                                     \
            q2 += c2 * c2;                                                     \
        }                                                                      \
        pd = fold1(pd);                                                        \
        q1 = fold1(q1);                                                        \
        q2 = fold1(q2);                                                        \
        if ((m & 1) == 0) {                                                    \
            const int grp = m >> 1;                                            \
            const int rb  = rh * 16 + quad * 4;                                \
            *reinterpret_cast<f32x4*>(&sRedAll[(g)][0][eh][grp][rb]) = pd;     \
            *reinterpret_cast<f32x4*>(&sRedAll[(g)][1][eh][grp][rb]) = q1;     \
            *reinterpret_cast<f32x4*>(&sRedAll[(g)][2][eh][grp][rb]) = q2;     \
        }                                                                      \
    }

    #pragma unroll
    for (int gp = 0; gp < 4; ++gp) {
        TILE_BODY(a1A, a2A, 2 * gp,     2 * gp + 2)   // even tile
        TILE_BODY(a1B, a2B, 2 * gp + 1, 2 * gp + 3)   // odd tile
    }
#undef TILE_BODY

    __syncthreads();   // the ONLY barrier: all 8 tiles' partials visible

    // ---- output: thread t -> tile = t>>5, row = t&31 (n = grpN*256 + t) ----
    {
        const int tile = tid >> 5;
        const int row  = tid & 31;
        float dot = 0.f, s1 = 0.f, s2 = 0.f;
        #pragma unroll
        for (int e2 = 0; e2 < 2; ++e2)
            #pragma unroll
            for (int gg = 0; gg < 8; ++gg) {
                dot += sRedAll[tile][0][e2][gg][row];
                s1  += sRedAll[tile][1][e2][gg][row];
                s2  += sRedAll[tile][2][e2][gg][row];
            }
        float n1 = fmaxf(sqrtf(s1), EPS);
        float n2 = fmaxf(sqrtf(s2), EPS);
        float tot = dot / (n1 * n2) + (p2a + p2b) + bk;
        __builtin_nontemporal_store(fmaxf(tot, 0.f), out + nOut * KK + k);
    }
}

extern "C" void kernel_launch(void* const* d_in, const int* in_sizes, int n_in,
                              void* d_out, int out_size, void* d_ws, size_t ws_size,
                              hipStream_t stream) {
    const float* x1 = (const float*)d_in[0];
    const float* x2 = (const float*)d_in[1];
    const float* W1 = (const float*)d_in[2];
    const float* W2 = (const float*)d_in[3];
    const float* V  = (const float*)d_in[4];
    const float* b  = (const float*)d_in[5];
    float* out = (float*)d_out;

    const int N = in_sizes[0] / DD;   // 32768

    __bf16* X1f = (__bf16*)d_ws;
    __bf16* X2f = X1f + (size_t)N * DD;
    __bf16* W1f = X2f + (size_t)N * DD;
    __bf16* W2f = W1f + (size_t)KK * DD * DD;
    float*  p2  = (float*)(W2f + (size_t)KK * DD * DD);   // [2][KK][N]

    const int cvt_half = N / 16;                  // 2048 blocks per tensor
    const int wf_half  = KK * DD * DD / 8 / 256;  // 256
    prep_kernel<<<2 * cvt_half + 2 * wf_half, 256, 0, stream>>>(
        x1, x2, W1, W2, V, X1f, X2f, W1f, W2f, p2, cvt_half, wf_half);

    const int groups = N / 256;                   // 128
    ntn_main<<<groups * KK, 256, 0, stream>>>(X1f, X2f, W1f, W2f, p2, b, out,
                                              groups / 8, N);
}